// Round 9
// baseline (208.949 us; speedup 1.0000x reference)
//
#include <hip/hip_runtime.h>
#include <stdint.h>

#define B_ 2
#define S_ 2048
#define D_ 1024
#define HD_ 64
#define DKV_ 256

typedef __attribute__((ext_vector_type(8))) __bf16 bf16x8;
typedef __attribute__((ext_vector_type(4))) float f32x4;
typedef __attribute__((ext_vector_type(4))) float float4v;
typedef __attribute__((ext_vector_type(4))) short s16x4;

__device__ __forceinline__ unsigned short f2bf(float f) {
  union { float f; uint32_t u; } v; v.f = f;
  uint32_t r = v.u + 0x7FFFu + ((v.u >> 16) & 1u);
  return (unsigned short)(r >> 16);
}

__device__ __forceinline__ void gload16(const void* g, void* l) {
  __builtin_amdgcn_global_load_lds(
      (const __attribute__((address_space(1))) uint32_t*)g,
      (__attribute__((address_space(3))) uint32_t*)l, 16, 0, 0);
}

__device__ __forceinline__ f32x4 mfma16(bf16x8 a, bf16x8 b, f32x4 c) {
  return __builtin_amdgcn_mfma_f32_16x16x32_bf16(a, b, c, 0, 0, 0);
}

// ---------------- prep: q fp32->bf16 AND all four W -> Wt[N][K] bf16 ----------------
// grid (208, 32): x<80 -> weight transpose-convert; x>=80 -> q convert.
__global__ void k_prep(const float* __restrict__ q, unsigned short* __restrict__ qbf,
                       const float* __restrict__ Wq, const float* __restrict__ Wk,
                       const float* __restrict__ Wv, const float* __restrict__ Wo,
                       unsigned short* __restrict__ WqT, unsigned short* __restrict__ WkT,
                       unsigned short* __restrict__ WvT, unsigned short* __restrict__ WoT) {
  const int x = blockIdx.x;
  if (x >= 80) {
    size_t i = (((size_t)(x - 80) * 32 + blockIdx.y) * 256 + threadIdx.x) * 4;
    float4v f = *(const float4v*)(q + i);
    s16x4 o;
#pragma unroll
    for (int r = 0; r < 4; ++r) o[r] = (short)f2bf(f[r]);
    *(s16x4*)(qbf + i) = o;
    return;
  }
  __shared__ unsigned short t[32][33];
  const float* W;
  unsigned short* Wt;
  int N, n0;
  if (x < 32)      { W = Wq; Wt = WqT; N = 1024; n0 = x * 32; }
  else if (x < 40) { W = Wk; Wt = WkT; N = 256;  n0 = (x - 32) * 32; }
  else if (x < 48) { W = Wv; Wt = WvT; N = 256;  n0 = (x - 40) * 32; }
  else             { W = Wo; Wt = WoT; N = 1024; n0 = (x - 48) * 32; }
  const int K = 1024, k0 = blockIdx.y * 32;
  int tx = threadIdx.x & 31, ty = threadIdx.x >> 5;
#pragma unroll
  for (int i = 0; i < 32; i += 8)
    t[ty + i][tx] = f2bf(W[(size_t)(k0 + ty + i) * N + n0 + tx]);
  __syncthreads();
#pragma unroll
  for (int i = 0; i < 32; i += 8)
    Wt[(size_t)(n0 + ty + i) * K + k0 + tx] = t[tx][ty + i];
}

// ---------------- GEMM body: 128(M) x 64(N) tile = A[M,K] * Bt[N,K]^T + bias ----------
// MODE 0: bf16 row-major C[M][N]; MODE 1: f32 row-major; MODE 2: bf16 written
// TRANSPOSED per batch into vpT[(b*DKV+col)][s] (fuses the old k_tbf).
// BK=64, 4 waves (2m x 2n), 48KB dbuf LDS -> 3 blocks/CU. Proven skeleton.
template <int MODE>
__device__ __forceinline__ void gemm_body64(
    const unsigned short* A, const unsigned short* Bt,
    const float* bias, void* Cout, int N, int K, int bx, int by) {
  __shared__ char lds[49152];
  const int lane = threadIdx.x & 63, wid = threadIdx.x >> 6;
  const int r15 = lane & 15, j = lane >> 4;
  const int wm = wid >> 1, wn = wid & 1;
  const size_t strideb = (size_t)K * 2;
  const char* Ab = (const char*)A + (size_t)bx * 128 * strideb;
  const char* Bb = (const char*)Bt + (size_t)by * 64 * strideb;
  const int srow = lane >> 3;
  const int scol = ((lane & 7) ^ srow) << 4;

  f32x4 acc[4][2];
#pragma unroll
  for (int a = 0; a < 4; ++a)
#pragma unroll
    for (int b = 0; b < 2; ++b) acc[a][b] = (f32x4){0.f, 0.f, 0.f, 0.f};

  auto stage = [&](int kt, int buf) {
    char* as = lds + buf * 24576;   // A: 128 rows x 128B = 16KB
    char* bs = as + 16384;          // B:  64 rows x 128B =  8KB
    const char* Ag = Ab + kt * 128;
    const char* Bg = Bb + kt * 128;
#pragma unroll
    for (int i = 0; i < 4; ++i) {
      int chunk = i * 4 + wid;
      gload16(Ag + (size_t)(chunk * 8 + srow) * strideb + scol, as + chunk * 1024);
    }
#pragma unroll
    for (int i = 0; i < 2; ++i) {
      int c2 = i * 4 + wid;
      gload16(Bg + (size_t)(c2 * 8 + srow) * strideb + scol, bs + c2 * 1024);
    }
  };

  stage(0, 0);
  __syncthreads();
  const int nk = K >> 6;
  const int ca0 = ((0 * 4 + j) ^ (r15 & 7)) << 4;
  const int ca1 = ((1 * 4 + j) ^ (r15 & 7)) << 4;

  for (int kt = 0; kt < nk; ++kt) {
    if (kt + 1 < nk) stage(kt + 1, (kt + 1) & 1);
    const char* as = lds + (kt & 1) * 24576;
    const char* bs = as + 16384;
    bf16x8 af[4][2], bfr[2][2];
#pragma unroll
    for (int mi = 0; mi < 4; ++mi) {
      int row = wm * 64 + mi * 16 + r15;
      af[mi][0] = *(const bf16x8*)(as + row * 128 + ca0);
      af[mi][1] = *(const bf16x8*)(as + row * 128 + ca1);
    }
#pragma unroll
    for (int ni = 0; ni < 2; ++ni) {
      int row = wn * 32 + ni * 16 + r15;
      bfr[ni][0] = *(const bf16x8*)(bs + row * 128 + ca0);
      bfr[ni][1] = *(const bf16x8*)(bs + row * 128 + ca1);
    }
#pragma unroll
    for (int kk = 0; kk < 2; ++kk)
#pragma unroll
      for (int mi = 0; mi < 4; ++mi)
#pragma unroll
        for (int ni = 0; ni < 2; ++ni)
          acc[mi][ni] = mfma16(af[mi][kk], bfr[ni][kk], acc[mi][ni]);
    __syncthreads();
  }

#pragma unroll
  for (int ni = 0; ni < 2; ++ni) {
    int col = by * 64 + wn * 32 + ni * 16 + r15;
    float bv = bias[col];
#pragma unroll
    for (int mi = 0; mi < 4; ++mi) {
      int row0 = bx * 128 + wm * 64 + mi * 16 + j * 4;
      if (MODE == 2) {
        // vpT[(b*DKV + col)][s], s = row0&2047 (+r consecutive) — 8B store
        s16x4 pb;
#pragma unroll
        for (int r = 0; r < 4; ++r) pb[r] = (short)f2bf(acc[mi][ni][r] + bv);
        size_t base = ((size_t)((row0 >> 11) * DKV_ + col)) * S_ + (row0 & 2047);
        *(s16x4*)((unsigned short*)Cout + base) = pb;
      } else {
#pragma unroll
        for (int r = 0; r < 4; ++r) {
          float v = acc[mi][ni][r] + bv;
          if (MODE == 1)
            ((float*)Cout)[(size_t)(row0 + r) * N + col] = v;
          else
            ((unsigned short*)Cout)[(size_t)(row0 + r) * N + col] = f2bf(v);
        }
      }
    }
  }
}

// merged QKV projections: grid (32, 24) = 768 blocks = 3/CU exactly.
// V (y>=20) writes vpT directly (transposed) — k_tbf fused away.
__global__ __launch_bounds__(256, 3) void k_gemm_qkv(
    const unsigned short* __restrict__ A,
    const unsigned short* __restrict__ WqT, const unsigned short* __restrict__ WkT,
    const unsigned short* __restrict__ WvT,
    const float* __restrict__ bq, const float* __restrict__ bk, const float* __restrict__ bv,
    unsigned short* __restrict__ qpB, unsigned short* __restrict__ kpB,
    unsigned short* __restrict__ vpT) {
  int y = blockIdx.y;
  if (y < 16)
    gemm_body64<0>(A, WqT, bq, qpB, 1024, 1024, blockIdx.x, y);
  else if (y < 20)
    gemm_body64<0>(A, WkT, bk, kpB, 256, 1024, blockIdx.x, y - 16);
  else
    gemm_body64<2>(A, WvT, bv, vpT, 256, 1024, blockIdx.x, y - 20);
}

// o-projection: grid (32, 16) = 512 blocks = 2/CU
__global__ __launch_bounds__(256, 3) void k_gemm_o(
    const unsigned short* __restrict__ A, const unsigned short* __restrict__ Bt,
    const float* __restrict__ bias, float* __restrict__ Cout) {
  gemm_body64<1>(A, Bt, bias, Cout, 1024, 1024, blockIdx.x, blockIdx.y);
}

// ---------------- fused GQA attention, LDS-staged, 2-pass ----------------
// 1024 blocks (blockIdx&7 = (b,kv) -> XCD L2 pinning), 4 waves x 16 q-rows.
// Pass A (lean, R7-proven): stage K only; QK + exp2 + lsum; vmcnt(0) +
//   __syncthreads per tile (no stores in flight -> vmcnt(0) is exact).
// Pass B: QK recompute + p=exp2*invl -> float4 attn store + PV (normalized).
//   COUNTED barrier (T3/T4): s_waitcnt vmcnt(4) allows this tile's 4 attn
//   stores to stay in flight across the raw s_barrier; FIFO vmcnt semantics
//   still guarantee the 4 staging loads (issued before the stores) and all
//   older stores have completed. Removes the per-tile store-ack drain that
//   __syncthreads' implicit vmcnt(0) forced.
__global__ __launch_bounds__(256, 4) void k_attn(
    const unsigned short* __restrict__ qp, const unsigned short* __restrict__ kp,
    const unsigned short* __restrict__ vpT, float* __restrict__ attn,
    unsigned short* __restrict__ ctx) {
  __shared__ char lds[40960];
  char* Ks = lds;            // 2 x 8KB : 64 k-rows x 128B, swz c^=row&7
  char* VTs = lds + 16384;   // 2 x 8KB : 64 d-rows x 128B, swz c^=row&7
  char* Ps = lds + 32768;    // 4 waves x 2KB : 16 q-rows x 128B, wave-private

  const int lane = threadIdx.x & 63, wid = threadIdx.x >> 6;
  const int r15 = lane & 15, j = lane >> 4;
  const int srow = lane >> 3;
  const int scol = ((lane & 7) ^ srow) << 4;

  const int lid = blockIdx.x;
  const int grp = lid & 7, inner = lid >> 3;   // grp: (b,kv); inner: 0..127
  const int h2 = inner >> 5, qt = inner & 31;  // h2: 0..3, qt: 0..31
  const int b = grp >> 2, kv = grp & 3, h = kv * 4 + h2;
  const int bh = b * 16 + h;
  const int q0 = qt * 64 + wid * 16;

  const char* kbase = (const char*)kp + ((size_t)(b * S_) * DKV_ + kv * HD_) * 2;
  const char* vtb = (const char*)vpT + ((size_t)(b * DKV_ + kv * HD_)) * S_ * 2;
  float* attnb = attn + ((size_t)bh * S_ + q0) * S_;
  char* psw = Ps + wid * 2048;

  auto stageK = [&](int kt, int buf) {
#pragma unroll
    for (int i = 0; i < 2; ++i)
      gload16(kbase + (size_t)(kt * 64 + wid * 16 + i * 8 + srow) * (DKV_ * 2) + scol,
              Ks + buf * 8192 + wid * 2048 + i * 1024);
  };
  auto stageVT = [&](int kt, int buf) {
#pragma unroll
    for (int i = 0; i < 2; ++i)
      gload16(vtb + (size_t)(wid * 16 + i * 8 + srow) * (S_ * 2) + kt * 128 + scol,
              VTs + buf * 8192 + wid * 2048 + i * 1024);
  };

  // Q fragments in registers; lane r15 owns q-row q0+r15
  const char* qr = (const char*)qp + ((size_t)(b * S_ + q0 + r15) * D_ + h * HD_) * 2;
  const bf16x8 bq0 = *(const bf16x8*)(qr + j * 16);
  const bf16x8 bq1 = *(const bf16x8*)(qr + 64 + j * 16);

  const float cs = 0.125f * 1.44269504088896f;  // SCALE * log2(e)

  auto qk = [&](const char* ks, f32x4 (&z)[4]) {
#pragma unroll
    for (int f = 0; f < 4; ++f) {
      int krow = f * 16 + r15;
      bf16x8 a0 = *(const bf16x8*)(ks + krow * 128 + ((j ^ (krow & 7)) << 4));
      bf16x8 a1 = *(const bf16x8*)(ks + krow * 128 + (((4 + j) ^ (krow & 7)) << 4));
      f32x4 t = mfma16(a0, bq0, (f32x4){0.f, 0.f, 0.f, 0.f});
      z[f] = mfma16(a1, bq1, t);
    }
  };

  // ---- pass A (lean): lsum only ----
  float lsum = 0.f;
  stageK(0, 0);
  asm volatile("s_waitcnt vmcnt(0)" ::: "memory");
  __syncthreads();
#pragma unroll 1
  for (int kt = 0; kt < 32; ++kt) {
    const int cur = kt & 1;
    if (kt + 1 < 32) stageK(kt + 1, cur ^ 1);
    f32x4 z[4];
    qk(Ks + cur * 8192, z);
#pragma unroll
    for (int f = 0; f < 4; ++f) {
      f32x4 p;
#pragma unroll
      for (int r = 0; r < 4; ++r) p[r] = exp2f(z[f][r] * cs);
      lsum += (p[0] + p[1]) + (p[2] + p[3]);
    }
    asm volatile("s_waitcnt vmcnt(0)" ::: "memory");
    __syncthreads();
  }

  lsum += __shfl_xor(lsum, 16, 64);
  lsum += __shfl_xor(lsum, 32, 64);
  const float invl = 1.f / lsum;

  // ---- pass B: attn store + PV (normalized p), counted-vmcnt barrier ----
  f32x4 o[4];
#pragma unroll
  for (int nf = 0; nf < 4; ++nf) o[nf] = (f32x4){0.f, 0.f, 0.f, 0.f};

  stageK(0, 0);   // both buffers free: all waves past pass-A's final barrier
  stageVT(0, 0);
  asm volatile("s_waitcnt vmcnt(0)" ::: "memory");
  __syncthreads();
#pragma unroll 1
  for (int kt = 0; kt < 32; ++kt) {
    const int cur = kt & 1;
    if (kt + 1 < 32) { stageK(kt + 1, cur ^ 1); stageVT(kt + 1, cur ^ 1); }
    f32x4 z[4];
    qk(Ks + cur * 8192, z);
#pragma unroll
    for (int f = 0; f < 4; ++f) {
      float4v pv;
#pragma unroll
      for (int r = 0; r < 4; ++r) pv[r] = exp2f(z[f][r] * cs) * invl;
      *(float4v*)(attnb + (size_t)r15 * S_ + kt * 64 + f * 16 + j * 4) = pv;
      s16x4 pb;
#pragma unroll
      for (int r = 0; r < 4; ++r) pb[r] = (short)f2bf(pv[r]);
      *(s16x4*)(psw + r15 * 128 +
                ((((f * 2 + (j >> 1)) ^ (r15 & 7)) << 4) | ((j & 1) * 8))) = pb;
    }
    const char* vs = VTs + cur * 8192;
#pragma unroll
    for (int ks2 = 0; ks2 < 2; ++ks2) {
      bf16x8 pa = *(const bf16x8*)(psw + r15 * 128 + (((ks2 * 4 + j) ^ (r15 & 7)) << 4));
#pragma unroll
      for (int nf = 0; nf < 4; ++nf) {
        int vrow = nf * 16 + r15;
        bf16x8 vb = *(const bf16x8*)(vs + vrow * 128 + (((ks2 * 4 + j) ^ (vrow & 7)) << 4));
        o[nf] = mfma16(pa, vb, o[nf]);
      }
    }
    // counted wait: 4 newest VMEM ops (this tile's attn stores) may remain in
    // flight; everything older — including this tile's 4 staging loads — is
    // guaranteed complete before any wave crosses the barrier.
    asm volatile("s_waitcnt vmcnt(4)" ::: "memory");
    __builtin_amdgcn_s_barrier();
  }

  // ctx write (bf16; o already normalized — D-fragment row q = j*4+r)
#pragma unroll
  for (int nf = 0; nf < 4; ++nf)
#pragma unroll
    for (int r = 0; r < 4; ++r)
      ctx[((size_t)(b * S_ + q0 + j * 4 + r)) * D_ + h * HD_ + nf * 16 + r15] =
          f2bf(o[nf][r]);
}

// ---------------- launch ----------------
extern "C" void kernel_launch(void* const* d_in, const int* in_sizes, int n_in,
                              void* d_out, int out_size, void* d_ws, size_t ws_size,
                              hipStream_t stream) {
  (void)in_sizes; (void)n_in; (void)out_size; (void)ws_size;
  const float* q = (const float*)d_in[0];
  const float* Wq = (const float*)d_in[1];
  const float* bq = (const float*)d_in[2];
  const float* Wk = (const float*)d_in[3];
  const float* bk = (const float*)d_in[4];
  const float* Wv = (const float*)d_in[5];
  const float* bv = (const float*)d_in[6];
  const float* Wo = (const float*)d_in[7];
  const float* bo = (const float*)d_in[8];

  char* ws = (char*)d_ws;
  unsigned short* qbf = (unsigned short*)(ws);                       // 8MB
  unsigned short* qpB = (unsigned short*)(ws + (8u << 20));          // 8MB
  unsigned short* kpB = (unsigned short*)(ws + (16u << 20));         // 2MB
  unsigned short* vpT = (unsigned short*)(ws + (20u << 20));         // 2MB
  unsigned short* ctx = (unsigned short*)(ws + (22u << 20));         // 8MB
  unsigned short* WqT = (unsigned short*)(ws + (30u << 20));         // 2MB
  unsigned short* WkT = (unsigned short*)(ws + (32u << 20));         // 512KB
  unsigned short* WvT = (unsigned short*)(ws + (32u << 20) + (512u << 10));
  unsigned short* WoT = (unsigned short*)(ws + (33u << 20));         // 2MB

  float* out = (float*)d_out;
  float* attn = out + (size_t)B_ * S_ * D_;

  k_prep<<<dim3(208, 32), 256, 0, stream>>>(q, qbf, Wq, Wk, Wv, Wo,
                                            WqT, WkT, WvT, WoT);

  k_gemm_qkv<<<dim3(32, 24), 256, 0, stream>>>(qbf, WqT, WkT, WvT, bq, bk, bv,
                                               qpB, kpB, vpT);

  k_attn<<<1024, 256, 0, stream>>>(qpB, kpB, vpT, attn, ctx);

  k_gemm_o<<<dim3(32, 16), 256, 0, stream>>>(ctx, WoT, bo, out);
}

// Round 10
// 196.450 us; speedup vs baseline: 1.0636x; 1.0636x over previous
//
#include <hip/hip_runtime.h>
#include <stdint.h>

#define B_ 2
#define S_ 2048
#define D_ 1024
#define HD_ 64
#define DKV_ 256

typedef __attribute__((ext_vector_type(8))) __bf16 bf16x8;
typedef __attribute__((ext_vector_type(4))) float f32x4;
typedef __attribute__((ext_vector_type(4))) float float4v;
typedef __attribute__((ext_vector_type(4))) short s16x4;

__device__ __forceinline__ unsigned short f2bf(float f) {
  union { float f; uint32_t u; } v; v.f = f;
  uint32_t r = v.u + 0x7FFFu + ((v.u >> 16) & 1u);
  return (unsigned short)(r >> 16);
}

__device__ __forceinline__ void gload16(const void* g, void* l) {
  __builtin_amdgcn_global_load_lds(
      (const __attribute__((address_space(1))) uint32_t*)g,
      (__attribute__((address_space(3))) uint32_t*)l, 16, 0, 0);
}

__device__ __forceinline__ f32x4 mfma16(bf16x8 a, bf16x8 b, f32x4 c) {
  return __builtin_amdgcn_mfma_f32_16x16x32_bf16(a, b, c, 0, 0, 0);
}

// ---------------- prep: q fp32->bf16 AND all four W -> Wt[N][K] bf16 ----------------
// grid (208, 32): x<80 -> weight transpose-convert; x>=80 -> q convert.
__global__ void k_prep(const float* __restrict__ q, unsigned short* __restrict__ qbf,
                       const float* __restrict__ Wq, const float* __restrict__ Wk,
                       const float* __restrict__ Wv, const float* __restrict__ Wo,
                       unsigned short* __restrict__ WqT, unsigned short* __restrict__ WkT,
                       unsigned short* __restrict__ WvT, unsigned short* __restrict__ WoT) {
  const int x = blockIdx.x;
  if (x >= 80) {
    size_t i = (((size_t)(x - 80) * 32 + blockIdx.y) * 256 + threadIdx.x) * 4;
    float4v f = *(const float4v*)(q + i);
    s16x4 o;
#pragma unroll
    for (int r = 0; r < 4; ++r) o[r] = (short)f2bf(f[r]);
    *(s16x4*)(qbf + i) = o;
    return;
  }
  __shared__ unsigned short t[32][33];
  const float* W;
  unsigned short* Wt;
  int N, n0;
  if (x < 32)      { W = Wq; Wt = WqT; N = 1024; n0 = x * 32; }
  else if (x < 40) { W = Wk; Wt = WkT; N = 256;  n0 = (x - 32) * 32; }
  else if (x < 48) { W = Wv; Wt = WvT; N = 256;  n0 = (x - 40) * 32; }
  else             { W = Wo; Wt = WoT; N = 1024; n0 = (x - 48) * 32; }
  const int K = 1024, k0 = blockIdx.y * 32;
  int tx = threadIdx.x & 31, ty = threadIdx.x >> 5;
#pragma unroll
  for (int i = 0; i < 32; i += 8)
    t[ty + i][tx] = f2bf(W[(size_t)(k0 + ty + i) * N + n0 + tx]);
  __syncthreads();
#pragma unroll
  for (int i = 0; i < 32; i += 8)
    Wt[(size_t)(n0 + ty + i) * K + k0 + tx] = t[tx][ty + i];
}

// ---------------- bf16 transpose per batch: src [R][C] -> dst [C][R] ----------------
__global__ void k_tbf(const unsigned short* __restrict__ src, unsigned short* __restrict__ dst,
                      int R, int C) {
  __shared__ unsigned short t[32][33];
  size_t base = (size_t)blockIdx.z * R * C;
  int c0 = blockIdx.x * 32, r0 = blockIdx.y * 32;
  int tx = threadIdx.x & 31, ty = threadIdx.x >> 5;
#pragma unroll
  for (int i = 0; i < 32; i += 8)
    t[ty + i][tx] = src[base + (size_t)(r0 + ty + i) * C + c0 + tx];
  __syncthreads();
#pragma unroll
  for (int i = 0; i < 32; i += 8)
    dst[base + (size_t)(c0 + ty + i) * R + r0 + tx] = t[tx][ty + i];
}

// ---------------- GEMM body: 128(M) x 64(N) tile = A[M,K] * Bt[N,K]^T + bias ----------
// MODE 0: bf16 row-major C[M][N]; MODE 1: f32 row-major.
// BK=64, 4 waves (2m x 2n), 48KB dbuf LDS -> 3 blocks/CU. Proven skeleton.
template <int MODE>
__device__ __forceinline__ void gemm_body64(
    const unsigned short* A, const unsigned short* Bt,
    const float* bias, void* Cout, int N, int K, int bx, int by) {
  __shared__ char lds[49152];
  const int lane = threadIdx.x & 63, wid = threadIdx.x >> 6;
  const int r15 = lane & 15, j = lane >> 4;
  const int wm = wid >> 1, wn = wid & 1;
  const size_t strideb = (size_t)K * 2;
  const char* Ab = (const char*)A + (size_t)bx * 128 * strideb;
  const char* Bb = (const char*)Bt + (size_t)by * 64 * strideb;
  const int srow = lane >> 3;
  const int scol = ((lane & 7) ^ srow) << 4;

  f32x4 acc[4][2];
#pragma unroll
  for (int a = 0; a < 4; ++a)
#pragma unroll
    for (int b = 0; b < 2; ++b) acc[a][b] = (f32x4){0.f, 0.f, 0.f, 0.f};

  auto stage = [&](int kt, int buf) {
    char* as = lds + buf * 24576;   // A: 128 rows x 128B = 16KB
    char* bs = as + 16384;          // B:  64 rows x 128B =  8KB
    const char* Ag = Ab + kt * 128;
    const char* Bg = Bb + kt * 128;
#pragma unroll
    for (int i = 0; i < 4; ++i) {
      int chunk = i * 4 + wid;
      gload16(Ag + (size_t)(chunk * 8 + srow) * strideb + scol, as + chunk * 1024);
    }
#pragma unroll
    for (int i = 0; i < 2; ++i) {
      int c2 = i * 4 + wid;
      gload16(Bg + (size_t)(c2 * 8 + srow) * strideb + scol, bs + c2 * 1024);
    }
  };

  stage(0, 0);
  __syncthreads();
  const int nk = K >> 6;
  const int ca0 = ((0 * 4 + j) ^ (r15 & 7)) << 4;
  const int ca1 = ((1 * 4 + j) ^ (r15 & 7)) << 4;

  for (int kt = 0; kt < nk; ++kt) {
    if (kt + 1 < nk) stage(kt + 1, (kt + 1) & 1);
    const char* as = lds + (kt & 1) * 24576;
    const char* bs = as + 16384;
    bf16x8 af[4][2], bfr[2][2];
#pragma unroll
    for (int mi = 0; mi < 4; ++mi) {
      int row = wm * 64 + mi * 16 + r15;
      af[mi][0] = *(const bf16x8*)(as + row * 128 + ca0);
      af[mi][1] = *(const bf16x8*)(as + row * 128 + ca1);
    }
#pragma unroll
    for (int ni = 0; ni < 2; ++ni) {
      int row = wn * 32 + ni * 16 + r15;
      bfr[ni][0] = *(const bf16x8*)(bs + row * 128 + ca0);
      bfr[ni][1] = *(const bf16x8*)(bs + row * 128 + ca1);
    }
#pragma unroll
    for (int kk = 0; kk < 2; ++kk)
#pragma unroll
      for (int mi = 0; mi < 4; ++mi)
#pragma unroll
        for (int ni = 0; ni < 2; ++ni)
          acc[mi][ni] = mfma16(af[mi][kk], bfr[ni][kk], acc[mi][ni]);
    __syncthreads();
  }

#pragma unroll
  for (int ni = 0; ni < 2; ++ni) {
    int col = by * 64 + wn * 32 + ni * 16 + r15;
    float bv = bias[col];
#pragma unroll
    for (int mi = 0; mi < 4; ++mi) {
      int row0 = bx * 128 + wm * 64 + mi * 16 + j * 4;
#pragma unroll
      for (int r = 0; r < 4; ++r) {
        float v = acc[mi][ni][r] + bv;
        if (MODE == 1)
          ((float*)Cout)[(size_t)(row0 + r) * N + col] = v;
        else
          ((unsigned short*)Cout)[(size_t)(row0 + r) * N + col] = f2bf(v);
      }
    }
  }
}

// merged QKV projections: grid (32, 24) = 768 blocks = 3/CU exactly
__global__ __launch_bounds__(256, 3) void k_gemm_qkv(
    const unsigned short* __restrict__ A,
    const unsigned short* __restrict__ WqT, const unsigned short* __restrict__ WkT,
    const unsigned short* __restrict__ WvT,
    const float* __restrict__ bq, const float* __restrict__ bk, const float* __restrict__ bv,
    unsigned short* __restrict__ qpB, unsigned short* __restrict__ kpB,
    unsigned short* __restrict__ vpB) {
  int y = blockIdx.y;
  if (y < 16)
    gemm_body64<0>(A, WqT, bq, qpB, 1024, 1024, blockIdx.x, y);
  else if (y < 20)
    gemm_body64<0>(A, WkT, bk, kpB, 256, 1024, blockIdx.x, y - 16);
  else
    gemm_body64<0>(A, WvT, bv, vpB, 256, 1024, blockIdx.x, y - 20);
}

// o-projection: grid (32, 16) = 512 blocks = 2/CU
__global__ __launch_bounds__(256, 3) void k_gemm_o(
    const unsigned short* __restrict__ A, const unsigned short* __restrict__ Bt,
    const float* __restrict__ bias, float* __restrict__ Cout) {
  gemm_body64<1>(A, Bt, bias, Cout, 1024, 1024, blockIdx.x, blockIdx.y);
}

// ---------------- fused GQA attention, LDS-staged, 2-pass ----------------
// 1024 blocks (blockIdx&7 = (b,kv) -> XCD L2 pinning), 4 waves x 16 q-rows.
// Pass A (lean, R7-proven): stage K only; QK + exp2 + lsum; vmcnt(0) +
//   __syncthreads per tile (no stores in flight -> vmcnt(0) is exact).
// Pass B: QK recompute + p=exp2*invl -> float4 attn store + PV (normalized).
//   COUNTED barrier (T3/T4): s_waitcnt vmcnt(4) lets this tile's 4 attn
//   stores stay in flight across the raw s_barrier; FIFO vmcnt semantics
//   still guarantee the 4 staging loads (issued before the stores) and all
//   older stores have completed.
__global__ __launch_bounds__(256, 4) void k_attn(
    const unsigned short* __restrict__ qp, const unsigned short* __restrict__ kp,
    const unsigned short* __restrict__ vpT, float* __restrict__ attn,
    unsigned short* __restrict__ ctx) {
  __shared__ char lds[40960];
  char* Ks = lds;            // 2 x 8KB : 64 k-rows x 128B, swz c^=row&7
  char* VTs = lds + 16384;   // 2 x 8KB : 64 d-rows x 128B, swz c^=row&7
  char* Ps = lds + 32768;    // 4 waves x 2KB : 16 q-rows x 128B, wave-private

  const int lane = threadIdx.x & 63, wid = threadIdx.x >> 6;
  const int r15 = lane & 15, j = lane >> 4;
  const int srow = lane >> 3;
  const int scol = ((lane & 7) ^ srow) << 4;

  const int lid = blockIdx.x;
  const int grp = lid & 7, inner = lid >> 3;   // grp: (b,kv); inner: 0..127
  const int h2 = inner >> 5, qt = inner & 31;  // h2: 0..3, qt: 0..31
  const int b = grp >> 2, kv = grp & 3, h = kv * 4 + h2;
  const int bh = b * 16 + h;
  const int q0 = qt * 64 + wid * 16;

  const char* kbase = (const char*)kp + ((size_t)(b * S_) * DKV_ + kv * HD_) * 2;
  const char* vtb = (const char*)vpT + ((size_t)(b * DKV_ + kv * HD_)) * S_ * 2;
  float* attnb = attn + ((size_t)bh * S_ + q0) * S_;
  char* psw = Ps + wid * 2048;

  auto stageK = [&](int kt, int buf) {
#pragma unroll
    for (int i = 0; i < 2; ++i)
      gload16(kbase + (size_t)(kt * 64 + wid * 16 + i * 8 + srow) * (DKV_ * 2) + scol,
              Ks + buf * 8192 + wid * 2048 + i * 1024);
  };
  auto stageVT = [&](int kt, int buf) {
#pragma unroll
    for (int i = 0; i < 2; ++i)
      gload16(vtb + (size_t)(wid * 16 + i * 8 + srow) * (S_ * 2) + kt * 128 + scol,
              VTs + buf * 8192 + wid * 2048 + i * 1024);
  };

  // Q fragments in registers; lane r15 owns q-row q0+r15
  const char* qr = (const char*)qp + ((size_t)(b * S_ + q0 + r15) * D_ + h * HD_) * 2;
  const bf16x8 bq0 = *(const bf16x8*)(qr + j * 16);
  const bf16x8 bq1 = *(const bf16x8*)(qr + 64 + j * 16);

  const float cs = 0.125f * 1.44269504088896f;  // SCALE * log2(e)

  auto qk = [&](const char* ks, f32x4 (&z)[4]) {
#pragma unroll
    for (int f = 0; f < 4; ++f) {
      int krow = f * 16 + r15;
      bf16x8 a0 = *(const bf16x8*)(ks + krow * 128 + ((j ^ (krow & 7)) << 4));
      bf16x8 a1 = *(const bf16x8*)(ks + krow * 128 + (((4 + j) ^ (krow & 7)) << 4));
      f32x4 t = mfma16(a0, bq0, (f32x4){0.f, 0.f, 0.f, 0.f});
      z[f] = mfma16(a1, bq1, t);
    }
  };

  // ---- pass A (lean): lsum only ----
  float lsum = 0.f;
  stageK(0, 0);
  asm volatile("s_waitcnt vmcnt(0)" ::: "memory");
  __syncthreads();
#pragma unroll 1
  for (int kt = 0; kt < 32; ++kt) {
    const int cur = kt & 1;
    if (kt + 1 < 32) stageK(kt + 1, cur ^ 1);
    f32x4 z[4];
    qk(Ks + cur * 8192, z);
#pragma unroll
    for (int f = 0; f < 4; ++f) {
      f32x4 p;
#pragma unroll
      for (int r = 0; r < 4; ++r) p[r] = exp2f(z[f][r] * cs);
      lsum += (p[0] + p[1]) + (p[2] + p[3]);
    }
    asm volatile("s_waitcnt vmcnt(0)" ::: "memory");
    __syncthreads();
  }

  lsum += __shfl_xor(lsum, 16, 64);
  lsum += __shfl_xor(lsum, 32, 64);
  const float invl = 1.f / lsum;

  // ---- pass B: attn store + PV (normalized p), counted-vmcnt barrier ----
  f32x4 o[4];
#pragma unroll
  for (int nf = 0; nf < 4; ++nf) o[nf] = (f32x4){0.f, 0.f, 0.f, 0.f};

  stageK(0, 0);   // both buffers free: all waves past pass-A's final barrier
  stageVT(0, 0);
  asm volatile("s_waitcnt vmcnt(0)" ::: "memory");
  __syncthreads();
#pragma unroll 1
  for (int kt = 0; kt < 32; ++kt) {
    const int cur = kt & 1;
    if (kt + 1 < 32) { stageK(kt + 1, cur ^ 1); stageVT(kt + 1, cur ^ 1); }
    f32x4 z[4];
    qk(Ks + cur * 8192, z);
#pragma unroll
    for (int f = 0; f < 4; ++f) {
      float4v pv;
#pragma unroll
      for (int r = 0; r < 4; ++r) pv[r] = exp2f(z[f][r] * cs) * invl;
      *(float4v*)(attnb + (size_t)r15 * S_ + kt * 64 + f * 16 + j * 4) = pv;
      s16x4 pb;
#pragma unroll
      for (int r = 0; r < 4; ++r) pb[r] = (short)f2bf(pv[r]);
      *(s16x4*)(psw + r15 * 128 +
                ((((f * 2 + (j >> 1)) ^ (r15 & 7)) << 4) | ((j & 1) * 8))) = pb;
    }
    const char* vs = VTs + cur * 8192;
#pragma unroll
    for (int ks2 = 0; ks2 < 2; ++ks2) {
      bf16x8 pa = *(const bf16x8*)(psw + r15 * 128 + (((ks2 * 4 + j) ^ (r15 & 7)) << 4));
#pragma unroll
      for (int nf = 0; nf < 4; ++nf) {
        int vrow = nf * 16 + r15;
        bf16x8 vb = *(const bf16x8*)(vs + vrow * 128 + (((ks2 * 4 + j) ^ (vrow & 7)) << 4));
        o[nf] = mfma16(pa, vb, o[nf]);
      }
    }
    // counted wait: 4 newest VMEM ops (this tile's attn stores) may remain in
    // flight; everything older — including this tile's 4 staging loads — is
    // guaranteed complete before any wave crosses the barrier.
    asm volatile("s_waitcnt vmcnt(4)" ::: "memory");
    __builtin_amdgcn_s_barrier();
  }

  // ctx write (bf16; o already normalized — D-fragment row q = j*4+r)
#pragma unroll
  for (int nf = 0; nf < 4; ++nf)
#pragma unroll
    for (int r = 0; r < 4; ++r)
      ctx[((size_t)(b * S_ + q0 + j * 4 + r)) * D_ + h * HD_ + nf * 16 + r15] =
          f2bf(o[nf][r]);
}

// ---------------- launch ----------------
extern "C" void kernel_launch(void* const* d_in, const int* in_sizes, int n_in,
                              void* d_out, int out_size, void* d_ws, size_t ws_size,
                              hipStream_t stream) {
  (void)in_sizes; (void)n_in; (void)out_size; (void)ws_size;
  const float* q = (const float*)d_in[0];
  const float* Wq = (const float*)d_in[1];
  const float* bq = (const float*)d_in[2];
  const float* Wk = (const float*)d_in[3];
  const float* bk = (const float*)d_in[4];
  const float* Wv = (const float*)d_in[5];
  const float* bv = (const float*)d_in[6];
  const float* Wo = (const float*)d_in[7];
  const float* bo = (const float*)d_in[8];

  char* ws = (char*)d_ws;
  unsigned short* qbf = (unsigned short*)(ws);                       // 8MB
  unsigned short* qpB = (unsigned short*)(ws + (8u << 20));          // 8MB
  unsigned short* kpB = (unsigned short*)(ws + (16u << 20));         // 2MB
  unsigned short* vpB = (unsigned short*)(ws + (18u << 20));         // 2MB
  unsigned short* vpT = (unsigned short*)(ws + (20u << 20));         // 2MB
  unsigned short* ctx = (unsigned short*)(ws + (22u << 20));         // 8MB
  unsigned short* WqT = (unsigned short*)(ws + (30u << 20));         // 2MB
  unsigned short* WkT = (unsigned short*)(ws + (32u << 20));         // 512KB
  unsigned short* WvT = (unsigned short*)(ws + (32u << 20) + (512u << 10));
  unsigned short* WoT = (unsigned short*)(ws + (33u << 20));         // 2MB

  float* out = (float*)d_out;
  float* attn = out + (size_t)B_ * S_ * D_;

  k_prep<<<dim3(208, 32), 256, 0, stream>>>(q, qbf, Wq, Wk, Wv, Wo,
                                            WqT, WkT, WvT, WoT);

  k_gemm_qkv<<<dim3(32, 24), 256, 0, stream>>>(qbf, WqT, WkT, WvT, bq, bk, bv,
                                               qpB, kpB, vpB);
  k_tbf<<<dim3(8, 64, 2), 256, 0, stream>>>(vpB, vpT, 2048, 256);

  k_attn<<<1024, 256, 0, stream>>>(qpB, kpB, vpT, attn, ctx);

  k_gemm_o<<<dim3(32, 16), 256, 0, stream>>>(ctx, WoT, bo, out);
}